// Round 22
// baseline (190.436 us; speedup 1.0000x reference)
//
#include <hip/hip_runtime.h>
#include <hip/hip_bf16.h>

// Color_Attention: transposed (channel) attention.
//   gram2_k: accepted plateau (~84us): 768 thr / 12 waves, register staging,
//   64-col phases; six structural variants all land 84-88us -> structural.
//   kD v2: 64-col chunks, grid (256,NB)=2048 blocks, ~130 regs/wave ->
//   ~4 waves/SIMD + multiple blocks/CU (occupancy lever, R7->R8 lesson).
//   Partials bf16 blocked 512B records in d_out scratch (NPART=32);
//   reduce_k<32> -> fp32 G (both triangles).
//   A_pre = Wq*G_ci*Wk^T ; nq = diag(Wq*G_cc*Wq^T); nk = diag(Wk*G_ii*Wk^T)
//   attn = softmax over head-diagonal 24x24 blocks of A_pre/(nq*nk)
//   P = Wo * blockdiag(attn) * Wv ; out = P @ input

typedef __attribute__((ext_vector_type(4))) float f32x4;
typedef __attribute__((ext_vector_type(8))) short short8;

#define MFMA16(a, b, c) __builtin_amdgcn_mfma_f32_16x16x32_bf16((a), (b), (c), 0, 0, 0)

__device__ __forceinline__ unsigned int pack_rne(float a, float b) {
  unsigned int ua = __float_as_uint(a), ub = __float_as_uint(b);
  ua += 0x7fffu + ((ua >> 16) & 1u);
  ub += 0x7fffu + ((ub >> 16) & 1u);
  return (ua >> 16) | (ub & 0xffff0000u);
}
__device__ __forceinline__ unsigned short bf16u_rne(float x) {
  unsigned int u = __float_as_uint(x);
  u += 0x7fffu + ((u >> 16) & 1u);
  return (unsigned short)(u >> 16);
}
union S8U { short8 s; unsigned int u[4]; };
__device__ __forceinline__ short8 load_cvt8(const float* p) {
  f32x4 x = *(const f32x4*)p;
  f32x4 y = *(const f32x4*)(p + 4);
  S8U r;
  r.u[0] = pack_rne(x[0], x[1]);
  r.u[1] = pack_rne(x[2], x[3]);
  r.u[2] = pack_rne(y[0], y[1]);
  r.u[3] = pack_rne(y[2], y[3]);
  return r.s;
}

#define HW 16384
#define CDIM 192
#define NB 8
#define GSZ (CDIM * CDIM)
#define NTILE 300     // blocked partial records per (b,strip): 12 pairs * 25 tiles
#define NPART 32      // partial sets (grid.x)
#define NPH 8         // 64-col phases per block: 32*8*64 = 16384
#define BROW 144      // gram bf16 buffer row stride (64 cols = 128B + 16B pad)
#define DROW 400      // kD BsT row stride: 192 bf16 (384B) + 16B pad

// ---------------- Kernel 0: transpose Wv -> bf16 WvT ----------------
__global__ void k0_wvt(const float* __restrict__ Wv, unsigned short* __restrict__ WvT) {
  int idx = blockIdx.x * 256 + threadIdx.x;
  if (idx < CDIM * CDIM) {
    int j = idx / CDIM, cp = idx % CDIM;
    WvT[idx] = bf16u_rne(Wv[(size_t)cp * CDIM + j]);
  }
}

// ---------------- Kernel B: gram Z*Z^T, register staging, 64-col phases -----
__device__ __forceinline__ short8 bfrag(const char* buf, int row, int lg, int ks2) {
  return *(const short8*)(buf + row * BROW + ks2 * 64 + lg * 16);
}

// wave W owns Z-tile rows {W, 23-W}: 25 upper-triangle tiles, static indexing.
template <int W>
__device__ __forceinline__ void pair_step(const char* bb, f32x4 (&acc)[25],
                                          int l15, int lg) {
#pragma unroll
  for (int ks2 = 0; ks2 < 2; ++ks2) {
    const short8 aT = bfrag(bb, W * 16 + l15, lg, ks2);
    const short8 aB = bfrag(bb, (23 - W) * 16 + l15, lg, ks2);
#pragma unroll
    for (int ct = W; ct < 24; ++ct) {
      const short8 b = bfrag(bb, ct * 16 + l15, lg, ks2);
      acc[ct - W] = MFMA16(aT, b, acc[ct - W]);
      if (ct >= 23 - W) acc[ct + 1] = MFMA16(aB, b, acc[ct + 1]);
    }
  }
}

__device__ __forceinline__ void pair_dispatch(int wp, const char* bb,
                                              f32x4 (&acc)[25], int l15, int lg) {
  switch (wp) {
    case 0: pair_step<0>(bb, acc, l15, lg); break;
    case 1: pair_step<1>(bb, acc, l15, lg); break;
    case 2: pair_step<2>(bb, acc, l15, lg); break;
    case 3: pair_step<3>(bb, acc, l15, lg); break;
    case 4: pair_step<4>(bb, acc, l15, lg); break;
    case 5: pair_step<5>(bb, acc, l15, lg); break;
    case 6: pair_step<6>(bb, acc, l15, lg); break;
    case 7: pair_step<7>(bb, acc, l15, lg); break;
    case 8: pair_step<8>(bb, acc, l15, lg); break;
    case 9: pair_step<9>(bb, acc, l15, lg); break;
    case 10: pair_step<10>(bb, acc, l15, lg); break;
    default: pair_step<11>(bb, acc, l15, lg); break;
  }
}

// grid (NPART, 8), 768 threads (12 waves). LDS = bbuf 55KB.
__global__ __launch_bounds__(768) void gram2_k(const float* __restrict__ input,
                                               const float* __restrict__ color,
                                               unsigned long long* __restrict__ part) {
  __shared__ __align__(16) char bbuf[384 * BROW];
  const int tid = threadIdx.x, wave = tid >> 6, lane = tid & 63;
  const int l15 = lane & 15, lg = (lane >> 4) & 3;
  const int strip = blockIdx.x, b = blockIdx.y;
  const int zrow = tid >> 1, half = tid & 1;
  const float* src = ((zrow < 192) ? (input + (size_t)zrow * HW)
                                   : (color + (size_t)(zrow - 192) * HW)) +
                     (size_t)b * CDIM * HW;
  const int col00 = strip * NPH * 64 + half * 32;

  f32x4 acc[25];
#pragma unroll
  for (int i = 0; i < 25; ++i) acc[i] = (f32x4){0.f, 0.f, 0.f, 0.f};

  f32x4 v0, v1, v2, v3, v4, v5, v6, v7;
  {
    const float* p = src + col00;
    v0 = *(const f32x4*)(p);
    v1 = *(const f32x4*)(p + 4);
    v2 = *(const f32x4*)(p + 8);
    v3 = *(const f32x4*)(p + 12);
    v4 = *(const f32x4*)(p + 16);
    v5 = *(const f32x4*)(p + 20);
    v6 = *(const f32x4*)(p + 24);
    v7 = *(const f32x4*)(p + 28);
  }

#pragma unroll 1
  for (int ph = 0; ph < NPH; ++ph) {
    __syncthreads();  // A: bbuf free
    {
      char* dst = bbuf + zrow * BROW + half * 64;
      S8U pk;
      pk.u[0] = pack_rne(v0[0], v0[1]);
      pk.u[1] = pack_rne(v0[2], v0[3]);
      pk.u[2] = pack_rne(v1[0], v1[1]);
      pk.u[3] = pack_rne(v1[2], v1[3]);
      *(short8*)(dst) = pk.s;
      pk.u[0] = pack_rne(v2[0], v2[1]);
      pk.u[1] = pack_rne(v2[2], v2[3]);
      pk.u[2] = pack_rne(v3[0], v3[1]);
      pk.u[3] = pack_rne(v3[2], v3[3]);
      *(short8*)(dst + 16) = pk.s;
      pk.u[0] = pack_rne(v4[0], v4[1]);
      pk.u[1] = pack_rne(v4[2], v4[3]);
      pk.u[2] = pack_rne(v5[0], v5[1]);
      pk.u[3] = pack_rne(v5[2], v5[3]);
      *(short8*)(dst + 32) = pk.s;
      pk.u[0] = pack_rne(v6[0], v6[1]);
      pk.u[1] = pack_rne(v6[2], v6[3]);
      pk.u[2] = pack_rne(v7[0], v7[1]);
      pk.u[3] = pack_rne(v7[2], v7[3]);
      *(short8*)(dst + 48) = pk.s;
    }
    __syncthreads();  // B: bbuf visible
    if (ph + 1 < NPH) {
      const float* p = src + col00 + (ph + 1) * 64;
      v0 = *(const f32x4*)(p);
      v1 = *(const f32x4*)(p + 4);
      v2 = *(const f32x4*)(p + 8);
      v3 = *(const f32x4*)(p + 12);
      v4 = *(const f32x4*)(p + 16);
      v5 = *(const f32x4*)(p + 20);
      v6 = *(const f32x4*)(p + 24);
      v7 = *(const f32x4*)(p + 28);
    }
    pair_dispatch(wave, bbuf, acc, l15, lg);
  }

  // ---- blocked flush, bf16: one contiguous 512B record per 16x16 tile ----
  unsigned long long* pbase = part + (size_t)(b * NPART + strip) * NTILE * 64;
#pragma unroll
  for (int s = 0; s < 25; ++s) {
    const unsigned long long pk =
        (unsigned long long)pack_rne(acc[s][0], acc[s][1]) |
        ((unsigned long long)pack_rne(acc[s][2], acc[s][3]) << 32);
    pbase[(size_t)(wave * 25 + s) * 64 + lane] = pk;
  }
}

// ---------------- reduce blocked bf16 partials -> fp32 G (both triangles) ---
template <int NP>
__global__ __launch_bounds__(256) void reduce_k(const unsigned long long* __restrict__ part,
                                                float* __restrict__ G) {
  const int b = blockIdx.y;
  const int T = blockIdx.x * 4 + (threadIdx.x >> 6);
  const int lane = threadIdx.x & 63;
  const unsigned long long* p = part + ((size_t)b * NP * NTILE + T) * 64 + lane;
  unsigned long long v[NP];
#pragma unroll
  for (int s = 0; s < NP; ++s) v[s] = p[(size_t)s * NTILE * 64];
  float s0 = 0.f, s1 = 0.f, s2 = 0.f, s3 = 0.f;
#pragma unroll
  for (int s = 0; s < NP; ++s) {
    const unsigned int lo = (unsigned int)v[s], hi = (unsigned int)(v[s] >> 32);
    s0 += __uint_as_float(lo << 16);
    s1 += __uint_as_float(lo & 0xffff0000u);
    s2 += __uint_as_float(hi << 16);
    s3 += __uint_as_float(hi & 0xffff0000u);
  }
  const int w = T / 25, s = T % 25;
  int rt, ct;
  if (s <= 23 - w) { rt = w; ct = w + s; }
  else { rt = 23 - w; ct = s - 1; }
  int type, gm, gn;
  if (ct < 12) { type = 2; gm = rt; gn = ct; }
  else if (rt < 12) { type = 0; gm = rt; gn = ct - 12; }
  else { type = 1; gm = rt - 12; gn = ct - 12; }
  float* Gm = G + ((size_t)type * NB + b) * GSZ;
  const int l15 = lane & 15, lg = lane >> 4;
  const int row0 = gm * 16 + lg * 4, col = gn * 16 + l15;
  const float sums[4] = {s0, s1, s2, s3};
#pragma unroll
  for (int r = 0; r < 4; ++r) Gm[(size_t)(row0 + r) * CDIM + col] = sums[r];
  if (type != 0 && rt != ct) {
#pragma unroll
    for (int r = 0; r < 4; ++r) Gm[(size_t)col * CDIM + (row0 + r)] = sums[r];
  }
}

// ---------------- Kernel 2a: A_pre (type0), nq (type1), nk (type2) ----------
__global__ __launch_bounds__(256) void k2a(const float* __restrict__ G,
                                           const float* __restrict__ Wq,
                                           const float* __restrict__ Wk,
                                           float* __restrict__ A_pre,
                                           float* __restrict__ nqk) {
  const int b = blockIdx.x, type = blockIdx.y;
  __shared__ __align__(16) unsigned short Hs[192][200];
  const int tid = threadIdx.x, wave = tid >> 6, lane = tid & 63;
  const int l15 = lane & 15, lg = lane >> 4, row0 = wave * 48;
  const float* W1 = (type == 2) ? Wk : Wq;
  const float* Gm = G + ((size_t)type * NB + b) * GSZ;

  f32x4 acc[3][12];
#pragma unroll
  for (int t = 0; t < 3; t++)
#pragma unroll
    for (int j = 0; j < 12; j++) acc[t][j] = (f32x4){0.f, 0.f, 0.f, 0.f};

  for (int ks = 0; ks < 192; ks += 32) {
    short8 afr[3];
#pragma unroll
    for (int t = 0; t < 3; t++)
      afr[t] = load_cvt8(W1 + (size_t)(row0 + t * 16 + l15) * CDIM + ks + lg * 8);
#pragma unroll
    for (int tj = 0; tj < 12; tj++) {
      short8 bfr = load_cvt8(Gm + (size_t)(tj * 16 + l15) * CDIM + ks + lg * 8);
#pragma unroll
      for (int t = 0; t < 3; t++) acc[t][tj] = MFMA16(afr[t], bfr, acc[t][tj]);
    }
  }
#pragma unroll
  for (int t = 0; t < 3; t++)
#pragma unroll
    for (int tj = 0; tj < 12; tj++)
#pragma unroll
      for (int r = 0; r < 4; r++)
        Hs[row0 + t * 16 + lg * 4 + r][tj * 16 + l15] = bf16u_rne(acc[t][tj][r]);
  __syncthreads();

  if (type == 0) {
    f32x4 a2[3][12];
#pragma unroll
    for (int t = 0; t < 3; t++)
#pragma unroll
      for (int j = 0; j < 12; j++) a2[t][j] = (f32x4){0.f, 0.f, 0.f, 0.f};
    for (int ks = 0; ks < 192; ks += 32) {
      short8 afr[3];
#pragma unroll
      for (int t = 0; t < 3; t++)
        afr[t] = *(const short8*)&Hs[row0 + t * 16 + l15][ks + lg * 8];
#pragma unroll
      for (int tj = 0; tj < 12; tj++) {
        short8 bfr = load_cvt8(Wk + (size_t)(tj * 16 + l15) * CDIM + ks + lg * 8);
#pragma unroll
        for (int t = 0; t < 3; t++) a2[t][tj] = MFMA16(afr[t], bfr, a2[t][tj]);
      }
    }
    float* Ab = A_pre + (size_t)b * GSZ;
#pragma unroll
    for (int t = 0; t < 3; t++)
#pragma unroll
      for (int tj = 0; tj < 12; tj++)
#pragma unroll
        for (int r = 0; r < 4; r++)
          Ab[(size_t)(row0 + t * 16 + lg * 4 + r) * CDIM + tj * 16 + l15] = a2[t][tj][r];
  } else {
    f32x4 a2[3];
#pragma unroll
    for (int t = 0; t < 3; t++) a2[t] = (f32x4){0.f, 0.f, 0.f, 0.f};
    for (int ks = 0; ks < 192; ks += 32) {
#pragma unroll
      for (int t = 0; t < 3; t++) {
        short8 afr = *(const short8*)&Hs[row0 + t * 16 + l15][ks + lg * 8];
        short8 bfr = load_cvt8(W1 + (size_t)(row0 + t * 16 + l15) * CDIM + ks + lg * 8);
        a2[t] = MFMA16(afr, bfr, a2[t]);
      }
    }
    float* dst = nqk + ((size_t)(type - 1) * NB + b) * CDIM;
#pragma unroll
    for (int t = 0; t < 3; t++)
#pragma unroll
      for (int r = 0; r < 4; r++)
        if (lg * 4 + r == l15) dst[row0 + t * 16 + l15] = a2[t][r];
  }
}

// ---------------- Kernel 2b: per-head softmax ----------------
__global__ void k2b(const float* __restrict__ A_pre, const float* __restrict__ nqk,
                    float* __restrict__ attnw) {
  const int b = blockIdx.x, tid = threadIdx.x;
  const int h = tid >> 5, r = tid & 31;
  if (r >= 24) return;
  const float* Ab = A_pre + (size_t)b * GSZ;
  const float* nq = nqk + (size_t)b * CDIM;
  const float* nk = nqk + (size_t)(NB + b) * CDIM;
  const int c = h * 24 + r;
  const float qn = rsqrtf(fmaxf(nq[c], 1e-24f));
  float e[24];
  float mx = -1e30f;
#pragma unroll
  for (int d = 0; d < 24; d++) {
    float kn = rsqrtf(fmaxf(nk[h * 24 + d], 1e-24f));
    float l = Ab[(size_t)c * CDIM + h * 24 + d] * qn * kn;
    e[d] = l;
    mx = fmaxf(mx, l);
  }
  float s = 0.f;
#pragma unroll
  for (int d = 0; d < 24; d++) {
    float x = __expf(e[d] - mx);
    e[d] = x;
    s += x;
  }
  const float inv = 1.0f / s;
  float* dst = attnw + (((size_t)b * NB + h) * 24 + r) * 24;
#pragma unroll
  for (int d = 0; d < 24; d++) dst[d] = e[d] * inv;
}

// ---------------- Kernel 3: P = Wo * blockdiag(attn) * Wv  (bf16 out) -------
__global__ __launch_bounds__(256) void k3(const float* __restrict__ attnw,
                                          const float* __restrict__ Wo,
                                          const unsigned short* __restrict__ WvT,
                                          unsigned short* __restrict__ Pbf) {
  const int b = blockIdx.x;
  __shared__ __align__(16) unsigned short AT[192][200];
  __shared__ __align__(16) unsigned short Ms[192][200];
  const int tid = threadIdx.x, wave = tid >> 6, lane = tid & 63;
  const int l15 = lane & 15, lg = lane >> 4, row0 = wave * 48;

  unsigned int* ATu = (unsigned int*)&AT[0][0];
  for (int i = tid; i < 192 * 100; i += 256) ATu[i] = 0u;
  __syncthreads();
  const float* at = attnw + (size_t)b * NB * 24 * 24;
  for (int i = tid; i < 4608; i += 256) {
    int h = i / 576, rem = i % 576, c = rem / 24, d = rem % 24;
    AT[h * 24 + d][h * 24 + c] = bf16u_rne(at[(h * 24 + c) * 24 + d]);
  }
  __syncthreads();

  f32x4 acc[3][12];
#pragma unroll
  for (int t = 0; t < 3; t++)
#pragma unroll
    for (int j = 0; j < 12; j++) acc[t][j] = (f32x4){0.f, 0.f, 0.f, 0.f};
  for (int ks = 0; ks < 192; ks += 32) {
    short8 afr[3];
#pragma unroll
    for (int t = 0; t < 3; t++)
      afr[t] = load_cvt8(Wo + (size_t)(row0 + t * 16 + l15) * CDIM + ks + lg * 8);
#pragma unroll
    for (int tj = 0; tj < 12; tj++) {
      short8 bfr = *(const short8*)&AT[tj * 16 + l15][ks + lg * 8];
#pragma unroll
      for (int t = 0; t < 3; t++) acc[t][tj] = MFMA16(afr[t], bfr, acc[t][tj]);
    }
  }
#pragma unroll
  for (int t = 0; t < 3; t++)
#pragma unroll
    for (int tj = 0; tj < 12; tj++)
#pragma unroll
      for (int r = 0; r < 4; r++)
        Ms[row0 + t * 16 + lg * 4 + r][tj * 16 + l15] = bf16u_rne(acc[t][tj][r]);
  __syncthreads();

  f32x4 a2[3][12];
#pragma unroll
  for (int t = 0; t < 3; t++)
#pragma unroll
    for (int j = 0; j < 12; j++) a2[t][j] = (f32x4){0.f, 0.f, 0.f, 0.f};
  for (int ks = 0; ks < 192; ks += 32) {
    short8 afr[3];
#pragma unroll
    for (int t = 0; t < 3; t++)
      afr[t] = *(const short8*)&Ms[row0 + t * 16 + l15][ks + lg * 8];
#pragma unroll
    for (int tj = 0; tj < 12; tj++) {
      short8 bfr = *(const short8*)(WvT + (size_t)(tj * 16 + l15) * CDIM + ks + lg * 8);
#pragma unroll
      for (int t = 0; t < 3; t++) a2[t][tj] = MFMA16(afr[t], bfr, a2[t][tj]);
    }
  }
  unsigned short* Pb = Pbf + (size_t)b * GSZ;
#pragma unroll
  for (int t = 0; t < 3; t++)
#pragma unroll
    for (int tj = 0; tj < 12; tj++)
#pragma unroll
      for (int r = 0; r < 4; r++)
        Pb[(size_t)(row0 + t * 16 + lg * 4 + r) * CDIM + tj * 16 + l15] = bf16u_rne(a2[t][tj][r]);
}

// ---------------- Kernel D v2: out = P @ input, 64-col chunks ----------------
// grid (HW/64=256, NB), 256 threads (4 waves). Per block: 192x64 output? no:
// full 192 rows x 64 cols of out. Staging: thread n4=(tid&15)*4 cols,
// kb0=(tid>>4)*12 rows; 12x f32x4 loads -> BsT[n][k] bf16 (DROW=400B rows).
// Wave w: rows w*48..w*48+47, acc[3][4]; ~130 regs -> ~4 waves/SIMD.
__global__ __launch_bounds__(256) void kD(const unsigned short* __restrict__ Pbf,
                                          const float* __restrict__ input,
                                          float* __restrict__ out) {
  const int nchunk = blockIdx.x, b = blockIdx.y;
  const int n0 = nchunk * 64;
  __shared__ __align__(16) char BsT[64 * DROW];
  const int tid = threadIdx.x, wave = tid >> 6, lane = tid & 63;
  const int l15 = lane & 15, lg = lane >> 4, row0 = wave * 48;

  {
    const int n4 = (tid & 15) * 4;
    const int kb0 = (tid >> 4) * 12;
    const float* src = input + (size_t)b * CDIM * HW + (size_t)kb0 * HW + n0 + n4;
    f32x4 w[12];
#pragma unroll
    for (int j = 0; j < 12; ++j)
      w[j] = *(const f32x4*)(src + (size_t)j * HW);
    __builtin_amdgcn_sched_barrier(0);
#pragma unroll
    for (int i = 0; i < 4; ++i) {
      const int n = n4 + i;
      char* dst = BsT + n * DROW + kb0 * 2;
#pragma unroll
      for (int q = 0; q < 3; ++q) {
        const unsigned long long pk =
            (unsigned long long)pack_rne(w[4 * q + 0][i], w[4 * q + 1][i]) |
            ((unsigned long long)pack_rne(w[4 * q + 2][i], w[4 * q + 3][i]) << 32);
        *(unsigned long long*)(dst + q * 8) = pk;
      }
    }
  }
  __syncthreads();

  f32x4 acc[3][4];
#pragma unroll
  for (int t = 0; t < 3; t++)
#pragma unroll
    for (int j = 0; j < 4; j++) acc[t][j] = (f32x4){0.f, 0.f, 0.f, 0.f};

  const unsigned short* Pb = Pbf + (size_t)b * GSZ;
#pragma unroll 2
  for (int ks = 0; ks < 6; ks++) {
    short8 afr[3];
#pragma unroll
    for (int t = 0; t < 3; t++)
      afr[t] = *(const short8*)(Pb + (size_t)(row0 + t * 16 + l15) * CDIM + ks * 32 + lg * 8);
#pragma unroll
    for (int tn = 0; tn < 4; tn++) {
      const int n = tn * 16 + l15;
      short8 bfr = *(const short8*)(BsT + n * DROW + ks * 64 + lg * 16);
#pragma unroll
      for (int t = 0; t < 3; t++) acc[t][tn] = MFMA16(afr[t], bfr, acc[t][tn]);
    }
  }
  float* ob = out + (size_t)b * CDIM * HW + n0;
#pragma unroll
  for (int t = 0; t < 3; t++)
#pragma unroll
    for (int tn = 0; tn < 4; tn++)
#pragma unroll
      for (int r = 0; r < 4; r++) {
        const int m = row0 + t * 16 + lg * 4 + r;
        ob[(size_t)m * HW + tn * 16 + l15] = acc[t][tn][r];
      }
}

// ---------------- launch ----------------
extern "C" void kernel_launch(void* const* d_in, const int* in_sizes, int n_in,
                              void* d_out, int out_size, void* d_ws, size_t ws_size,
                              hipStream_t stream) {
  const float* input = (const float*)d_in[0];
  const float* color = (const float*)d_in[1];
  const float* Wq = (const float*)d_in[2];
  const float* Wk = (const float*)d_in[3];
  const float* Wv = (const float*)d_in[4];
  const float* Wo = (const float*)d_in[5];
  float* out = (float*)d_out;
  char* ws = (char*)d_ws;

  const size_t OFF_G = 0;                        // 3*8*192*192*4 = 3538944
  const size_t OFF_APRE = 3538944;               // 8*192*192*4  = 1179648
  const size_t OFF_NQK = OFF_APRE + 1179648;     // 2*8*192*4    = 12288
  const size_t OFF_ATT = OFF_NQK + 12288;        // 8*8*24*24*4  = 147456
  const size_t OFF_WVT = OFF_ATT + 147456;       // 192*192*2    = 73728
  const size_t OFF_PBF = OFF_WVT + 73728;        // 8*192*192*2  = 589824

  float* G = (float*)(ws + OFF_G);
  float* A_pre = (float*)(ws + OFF_APRE);
  float* nqk = (float*)(ws + OFF_NQK);
  float* attnw = (float*)(ws + OFF_ATT);
  unsigned short* WvT = (unsigned short*)(ws + OFF_WVT);
  unsigned short* Pbf = (unsigned short*)(ws + OFF_PBF);

  // Partials (bf16 blocked records) in d_out scratch:
  // 32*8*300*512 = 39,321,600 B <= out_size*4 = 100,663,296 B.
  // reduce_k consumes them before kD overwrites d_out.
  unsigned long long* part = (unsigned long long*)d_out;

  k0_wvt<<<dim3(144), dim3(256), 0, stream>>>(Wv, WvT);
  gram2_k<<<dim3(NPART, NB), dim3(768), 0, stream>>>(input, color, part);
  reduce_k<NPART><<<dim3(75, NB), dim3(256), 0, stream>>>(part, G);
  k2a<<<dim3(NB, 3), dim3(256), 0, stream>>>(G, Wq, Wk, A_pre, nqk);
  k2b<<<dim3(NB), dim3(256), 0, stream>>>(A_pre, nqk, attnw);
  k3<<<dim3(NB), dim3(256), 0, stream>>>(attnw, Wo, WvT, Pbf);
  kD<<<dim3(HW / 64, NB), dim3(256), 0, stream>>>(Pbf, input, out);
}

// Round 23
// 180.866 us; speedup vs baseline: 1.0529x; 1.0529x over previous
//
#include <hip/hip_runtime.h>
#include <hip/hip_bf16.h>

// Color_Attention: transposed (channel) attention. BEST-MEASURED CONFIG (R19,
// 181.0us): gram2_k with register staging (32-col chunk-pairs), kD v1
// (128-col chunks). R20-R22 variants (64-col gram phases, kD 64-col) were
// neutral-to-worse; reverting to the measured optimum.
//   gram2_k: 768 thr / 12 waves, per-lane f32x4 loads -> in-register bf16
//   pack -> ds_write_b128 into bbuf (80B rows). Loads for pair cp+1 issued
//   before MFMA of pair cp. LDS = bbuf only (30KB). __syncthreads() sync.
//   MFMA16 1 K-step/pair; wave w owns row-pair (w,23-w) = 25 tiles.
//   Partials bf16 blocked 512B records in d_out scratch (NPART=32);
//   reduce_k<32> -> fp32 G (both triangles).
//   A_pre = Wq*G_ci*Wk^T ; nq = diag(Wq*G_cc*Wq^T); nk = diag(Wk*G_ii*Wk^T)
//   attn = softmax over head-diagonal 24x24 blocks of A_pre/(nq*nk)
//   P = Wo * blockdiag(attn) * Wv ; out = P @ input

typedef __attribute__((ext_vector_type(4))) float f32x4;
typedef __attribute__((ext_vector_type(8))) short short8;

#define MFMA16(a, b, c) __builtin_amdgcn_mfma_f32_16x16x32_bf16((a), (b), (c), 0, 0, 0)

__device__ __forceinline__ unsigned int pack_rne(float a, float b) {
  unsigned int ua = __float_as_uint(a), ub = __float_as_uint(b);
  ua += 0x7fffu + ((ua >> 16) & 1u);
  ub += 0x7fffu + ((ub >> 16) & 1u);
  return (ua >> 16) | (ub & 0xffff0000u);
}
__device__ __forceinline__ unsigned short bf16u_rne(float x) {
  unsigned int u = __float_as_uint(x);
  u += 0x7fffu + ((u >> 16) & 1u);
  return (unsigned short)(u >> 16);
}
union S8U { short8 s; unsigned int u[4]; };
__device__ __forceinline__ short8 load_cvt8(const float* p) {
  f32x4 x = *(const f32x4*)p;
  f32x4 y = *(const f32x4*)(p + 4);
  S8U r;
  r.u[0] = pack_rne(x[0], x[1]);
  r.u[1] = pack_rne(x[2], x[3]);
  r.u[2] = pack_rne(y[0], y[1]);
  r.u[3] = pack_rne(y[2], y[3]);
  return r.s;
}

#define HW 16384
#define CDIM 192
#define NB 8
#define GSZ (CDIM * CDIM)
#define NTILE 300     // blocked partial records per (b,strip): 12 pairs * 25 tiles
#define NPART 32      // partial sets (grid.x)
#define NCP 16        // chunk-pairs (32 cols) per block: 32*16*32 = 16384
#define BROW 80       // bf16 buffer row stride (reads 2-way/free)

// ---------------- Kernel 0: transpose Wv -> bf16 WvT ----------------
__global__ void k0_wvt(const float* __restrict__ Wv, unsigned short* __restrict__ WvT) {
  int idx = blockIdx.x * 256 + threadIdx.x;
  if (idx < CDIM * CDIM) {
    int j = idx / CDIM, cp = idx % CDIM;
    WvT[idx] = bf16u_rne(Wv[(size_t)cp * CDIM + j]);
  }
}

// ---------------- Kernel B: gram Z*Z^T, register staging -------------
__device__ __forceinline__ short8 bfrag(const char* buf, int row, int lg) {
  return *(const short8*)(buf + row * BROW + lg * 16);
}

// wave W owns Z-tile rows {W, 23-W}: 25 upper-triangle tiles, static indexing.
// slots: row W, col ct -> ct-W (ct=W..23); row 23-W, col ct -> ct+1 (ct>=23-W)
template <int W>
__device__ __forceinline__ void pair_step(const char* bb, f32x4 (&acc)[25],
                                          int l15, int lg) {
  const short8 aT = bfrag(bb, W * 16 + l15, lg);
  const short8 aB = bfrag(bb, (23 - W) * 16 + l15, lg);
#pragma unroll
  for (int ct = W; ct < 24; ++ct) {
    const short8 b = bfrag(bb, ct * 16 + l15, lg);
    acc[ct - W] = MFMA16(aT, b, acc[ct - W]);
    if (ct >= 23 - W) acc[ct + 1] = MFMA16(aB, b, acc[ct + 1]);
  }
}

__device__ __forceinline__ void pair_dispatch(int wp, const char* bb,
                                              f32x4 (&acc)[25], int l15, int lg) {
  switch (wp) {
    case 0: pair_step<0>(bb, acc, l15, lg); break;
    case 1: pair_step<1>(bb, acc, l15, lg); break;
    case 2: pair_step<2>(bb, acc, l15, lg); break;
    case 3: pair_step<3>(bb, acc, l15, lg); break;
    case 4: pair_step<4>(bb, acc, l15, lg); break;
    case 5: pair_step<5>(bb, acc, l15, lg); break;
    case 6: pair_step<6>(bb, acc, l15, lg); break;
    case 7: pair_step<7>(bb, acc, l15, lg); break;
    case 8: pair_step<8>(bb, acc, l15, lg); break;
    case 9: pair_step<9>(bb, acc, l15, lg); break;
    case 10: pair_step<10>(bb, acc, l15, lg); break;
    default: pair_step<11>(bb, acc, l15, lg); break;
  }
}

// grid (NPART, 8), 768 threads (12 waves). LDS = bbuf 30KB only.
// Thread owns 2 staging units of 32B per pair: unit0 = input row (tid>>2),
// unit1 = color row (tid>>2); sub = tid&3 selects 8-float piece of the
// 32-col pair span. bbuf row = 32 contiguous bf16 cols (pair), 80B stride.
// Schedule per pair cp:
//   sync A (bbuf free) -> pack regs -> ds_write -> sync B (bbuf ready)
//   -> issue loads for pair cp+1 (fly under MFMA) -> MFMA on bbuf.
__global__ __launch_bounds__(768) void gram2_k(const float* __restrict__ input,
                                               const float* __restrict__ color,
                                               unsigned long long* __restrict__ part) {
  __shared__ __align__(16) char bbuf[384 * BROW];
  const int tid = threadIdx.x, wave = tid >> 6, lane = tid & 63;
  const int l15 = lane & 15, lg = (lane >> 4) & 3;
  const int strip = blockIdx.x, b = blockIdx.y;
  const int row = tid >> 2, sub = tid & 3;
  const float* ip = input + (size_t)b * CDIM * HW + (size_t)row * HW;
  const float* cp_ = color + (size_t)b * CDIM * HW + (size_t)row * HW;
  const int ch0 = strip * NCP * 2;  // base chunk (16-col units)

  f32x4 acc[25];
#pragma unroll
  for (int i = 0; i < 25; ++i) acc[i] = (f32x4){0.f, 0.f, 0.f, 0.f};

  // per-pair column base (floats) for this thread's piece
  f32x4 vi0, vi1, vc0, vc1;
  {
    const int colf = (ch0 + (sub >> 1)) * 16 + (sub & 1) * 8;
    vi0 = *(const f32x4*)(ip + colf);
    vi1 = *(const f32x4*)(ip + colf + 4);
    vc0 = *(const f32x4*)(cp_ + colf);
    vc1 = *(const f32x4*)(cp_ + colf + 4);
  }

#pragma unroll 1
  for (int cpi = 0; cpi < NCP; ++cpi) {
    __syncthreads();  // A: bbuf free (all waves done with prior MFMA)
    {
      S8U pk;
      pk.u[0] = pack_rne(vi0[0], vi0[1]);
      pk.u[1] = pack_rne(vi0[2], vi0[3]);
      pk.u[2] = pack_rne(vi1[0], vi1[1]);
      pk.u[3] = pack_rne(vi1[2], vi1[3]);
      *(short8*)(bbuf + row * BROW + sub * 16) = pk.s;
      pk.u[0] = pack_rne(vc0[0], vc0[1]);
      pk.u[1] = pack_rne(vc0[2], vc0[3]);
      pk.u[2] = pack_rne(vc1[0], vc1[1]);
      pk.u[3] = pack_rne(vc1[2], vc1[3]);
      *(short8*)(bbuf + (192 + row) * BROW + sub * 16) = pk.s;
    }
    __syncthreads();  // B: bbuf visible
    if (cpi + 1 < NCP) {
      const int colf = (ch0 + 2 * (cpi + 1) + (sub >> 1)) * 16 + (sub & 1) * 8;
      vi0 = *(const f32x4*)(ip + colf);
      vi1 = *(const f32x4*)(ip + colf + 4);
      vc0 = *(const f32x4*)(cp_ + colf);
      vc1 = *(const f32x4*)(cp_ + colf + 4);
    }
    pair_dispatch(wave, bbuf, acc, l15, lg);
  }

  // ---- blocked flush, bf16: one contiguous 512B record per 16x16 tile ----
  unsigned long long* pbase = part + (size_t)(b * NPART + strip) * NTILE * 64;
#pragma unroll
  for (int s = 0; s < 25; ++s) {
    const unsigned long long pk =
        (unsigned long long)pack_rne(acc[s][0], acc[s][1]) |
        ((unsigned long long)pack_rne(acc[s][2], acc[s][3]) << 32);
    pbase[(size_t)(wave * 25 + s) * 64 + lane] = pk;
  }
}

// ---------------- reduce blocked bf16 partials -> fp32 G (both triangles) ---
// grid (75, NB), 256 threads: 4 records per block, NP fully unrolled.
template <int NP>
__global__ __launch_bounds__(256) void reduce_k(const unsigned long long* __restrict__ part,
                                                float* __restrict__ G) {
  const int b = blockIdx.y;
  const int T = blockIdx.x * 4 + (threadIdx.x >> 6);
  const int lane = threadIdx.x & 63;
  const unsigned long long* p = part + ((size_t)b * NP * NTILE + T) * 64 + lane;
  unsigned long long v[NP];
#pragma unroll
  for (int s = 0; s < NP; ++s) v[s] = p[(size_t)s * NTILE * 64];
  float s0 = 0.f, s1 = 0.f, s2 = 0.f, s3 = 0.f;
#pragma unroll
  for (int s = 0; s < NP; ++s) {
    const unsigned int lo = (unsigned int)v[s], hi = (unsigned int)(v[s] >> 32);
    s0 += __uint_as_float(lo << 16);
    s1 += __uint_as_float(lo & 0xffff0000u);
    s2 += __uint_as_float(hi << 16);
    s3 += __uint_as_float(hi & 0xffff0000u);
  }
  // decode record T -> Z-tile (rt, ct) with rt <= ct
  const int w = T / 25, s = T % 25;
  int rt, ct;
  if (s <= 23 - w) { rt = w; ct = w + s; }
  else { rt = 23 - w; ct = s - 1; }
  // map Z-tile to G type: rows 0..11 = I, 12..23 = C
  int type, gm, gn;
  if (ct < 12) { type = 2; gm = rt; gn = ct; }            // I*I^T
  else if (rt < 12) { type = 0; gm = rt; gn = ct - 12; }  // I*C^T (full)
  else { type = 1; gm = rt - 12; gn = ct - 12; }          // C*C^T
  float* Gm = G + ((size_t)type * NB + b) * GSZ;
  const int l15 = lane & 15, lg = lane >> 4;
  const int row0 = gm * 16 + lg * 4, col = gn * 16 + l15;
  const float sums[4] = {s0, s1, s2, s3};
#pragma unroll
  for (int r = 0; r < 4; ++r) Gm[(size_t)(row0 + r) * CDIM + col] = sums[r];
  if (type != 0 && rt != ct) {
#pragma unroll
    for (int r = 0; r < 4; ++r) Gm[(size_t)col * CDIM + (row0 + r)] = sums[r];
  }
}

// ---------------- Kernel 2a: A_pre (type0), nq (type1), nk (type2) ----------
__global__ __launch_bounds__(256) void k2a(const float* __restrict__ G,
                                           const float* __restrict__ Wq,
                                           const float* __restrict__ Wk,
                                           float* __restrict__ A_pre,
                                           float* __restrict__ nqk) {
  const int b = blockIdx.x, type = blockIdx.y;
  __shared__ __align__(16) unsigned short Hs[192][200];
  const int tid = threadIdx.x, wave = tid >> 6, lane = tid & 63;
  const int l15 = lane & 15, lg = lane >> 4, row0 = wave * 48;
  const float* W1 = (type == 2) ? Wk : Wq;
  const float* Gm = G + ((size_t)type * NB + b) * GSZ;

  f32x4 acc[3][12];
#pragma unroll
  for (int t = 0; t < 3; t++)
#pragma unroll
    for (int j = 0; j < 12; j++) acc[t][j] = (f32x4){0.f, 0.f, 0.f, 0.f};

  for (int ks = 0; ks < 192; ks += 32) {
    short8 afr[3];
#pragma unroll
    for (int t = 0; t < 3; t++)
      afr[t] = load_cvt8(W1 + (size_t)(row0 + t * 16 + l15) * CDIM + ks + lg * 8);
#pragma unroll
    for (int tj = 0; tj < 12; tj++) {
      short8 bfr = load_cvt8(Gm + (size_t)(tj * 16 + l15) * CDIM + ks + lg * 8);
#pragma unroll
      for (int t = 0; t < 3; t++) acc[t][tj] = MFMA16(afr[t], bfr, acc[t][tj]);
    }
  }
#pragma unroll
  for (int t = 0; t < 3; t++)
#pragma unroll
    for (int tj = 0; tj < 12; tj++)
#pragma unroll
      for (int r = 0; r < 4; r++)
        Hs[row0 + t * 16 + lg * 4 + r][tj * 16 + l15] = bf16u_rne(acc[t][tj][r]);
  __syncthreads();

  if (type == 0) {
    f32x4 a2[3][12];
#pragma unroll
    for (int t = 0; t < 3; t++)
#pragma unroll
      for (int j = 0; j < 12; j++) a2[t][j] = (f32x4){0.f, 0.f, 0.f, 0.f};
    for (int ks = 0; ks < 192; ks += 32) {
      short8 afr[3];
#pragma unroll
      for (int t = 0; t < 3; t++)
        afr[t] = *(const short8*)&Hs[row0 + t * 16 + l15][ks + lg * 8];
#pragma unroll
      for (int tj = 0; tj < 12; tj++) {
        short8 bfr = load_cvt8(Wk + (size_t)(tj * 16 + l15) * CDIM + ks + lg * 8);
#pragma unroll
        for (int t = 0; t < 3; t++) a2[t][tj] = MFMA16(afr[t], bfr, a2[t][tj]);
      }
    }
    float* Ab = A_pre + (size_t)b * GSZ;
#pragma unroll
    for (int t = 0; t < 3; t++)
#pragma unroll
      for (int tj = 0; tj < 12; tj++)
#pragma unroll
        for (int r = 0; r < 4; r++)
          Ab[(size_t)(row0 + t * 16 + lg * 4 + r) * CDIM + tj * 16 + l15] = a2[t][tj][r];
  } else {
    f32x4 a2[3];
#pragma unroll
    for (int t = 0; t < 3; t++) a2[t] = (f32x4){0.f, 0.f, 0.f, 0.f};
    for (int ks = 0; ks < 192; ks += 32) {
#pragma unroll
      for (int t = 0; t < 3; t++) {
        short8 afr = *(const short8*)&Hs[row0 + t * 16 + l15][ks + lg * 8];
        short8 bfr = load_cvt8(W1 + (size_t)(row0 + t * 16 + l15) * CDIM + ks + lg * 8);
        a2[t] = MFMA16(afr, bfr, a2[t]);
      }
    }
    float* dst = nqk + ((size_t)(type - 1) * NB + b) * CDIM;
#pragma unroll
    for (int t = 0; t < 3; t++)
#pragma unroll
      for (int r = 0; r < 4; r++)
        if (lg * 4 + r == l15) dst[row0 + t * 16 + l15] = a2[t][r];
  }
}

// ---------------- Kernel 2b: per-head softmax ----------------
__global__ void k2b(const float* __restrict__ A_pre, const float* __restrict__ nqk,
                    float* __restrict__ attnw) {
  const int b = blockIdx.x, tid = threadIdx.x;
  const int h = tid >> 5, r = tid & 31;
  if (r >= 24) return;
  const float* Ab = A_pre + (size_t)b * GSZ;
  const float* nq = nqk + (size_t)b * CDIM;
  const float* nk = nqk + (size_t)(NB + b) * CDIM;
  const int c = h * 24 + r;
  const float qn = rsqrtf(fmaxf(nq[c], 1e-24f));
  float e[24];
  float mx = -1e30f;
#pragma unroll
  for (int d = 0; d < 24; d++) {
    float kn = rsqrtf(fmaxf(nk[h * 24 + d], 1e-24f));
    float l = Ab[(size_t)c * CDIM + h * 24 + d] * qn * kn;
    e[d] = l;
    mx = fmaxf(mx, l);
  }
  float s = 0.f;
#pragma unroll
  for (int d = 0; d < 24; d++) {
    float x = __expf(e[d] - mx);
    e[d] = x;
    s += x;
  }
  const float inv = 1.0f / s;
  float* dst = attnw + (((size_t)b * NB + h) * 24 + r) * 24;
#pragma unroll
  for (int d = 0; d < 24; d++) dst[d] = e[d] * inv;
}

// ---------------- Kernel 3: P = Wo * blockdiag(attn) * Wv  (bf16 out) -------
__global__ __launch_bounds__(256) void k3(const float* __restrict__ attnw,
                                          const float* __restrict__ Wo,
                                          const unsigned short* __restrict__ WvT,
                                          unsigned short* __restrict__ Pbf) {
  const int b = blockIdx.x;
  __shared__ __align__(16) unsigned short AT[192][200];
  __shared__ __align__(16) unsigned short Ms[192][200];
  const int tid = threadIdx.x, wave = tid >> 6, lane = tid & 63;
  const int l15 = lane & 15, lg = lane >> 4, row0 = wave * 48;

  unsigned int* ATu = (unsigned int*)&AT[0][0];
  for (int i = tid; i < 192 * 100; i += 256) ATu[i] = 0u;
  __syncthreads();
  const float* at = attnw + (size_t)b * NB * 24 * 24;
  for (int i = tid; i < 4608; i += 256) {
    int h = i / 576, rem = i % 576, c = rem / 24, d = rem % 24;
    AT[h * 24 + d][h * 24 + c] = bf16u_rne(at[(h * 24 + c) * 24 + d]);
  }
  __syncthreads();

  f32x4 acc[3][12];
#pragma unroll
  for (int t = 0; t < 3; t++)
#pragma unroll
    for (int j = 0; j < 12; j++) acc[t][j] = (f32x4){0.f, 0.f, 0.f, 0.f};
  for (int ks = 0; ks < 192; ks += 32) {
    short8 afr[3];
#pragma unroll
    for (int t = 0; t < 3; t++)
      afr[t] = load_cvt8(Wo + (size_t)(row0 + t * 16 + l15) * CDIM + ks + lg * 8);
#pragma unroll
    for (int tj = 0; tj < 12; tj++) {
      short8 bfr = *(const short8*)&AT[tj * 16 + l15][ks + lg * 8];
#pragma unroll
      for (int t = 0; t < 3; t++) acc[t][tj] = MFMA16(afr[t], bfr, acc[t][tj]);
    }
  }
#pragma unroll
  for (int t = 0; t < 3; t++)
#pragma unroll
    for (int tj = 0; tj < 12; tj++)
#pragma unroll
      for (int r = 0; r < 4; r++)
        Ms[row0 + t * 16 + lg * 4 + r][tj * 16 + l15] = bf16u_rne(acc[t][tj][r]);
  __syncthreads();

  f32x4 a2[3][12];
#pragma unroll
  for (int t = 0; t < 3; t++)
#pragma unroll
    for (int j = 0; j < 12; j++) a2[t][j] = (f32x4){0.f, 0.f, 0.f, 0.f};
  for (int ks = 0; ks < 192; ks += 32) {
    short8 afr[3];
#pragma unroll
    for (int t = 0; t < 3; t++)
      afr[t] = *(const short8*)&Ms[row0 + t * 16 + l15][ks + lg * 8];
#pragma unroll
    for (int tj = 0; tj < 12; tj++) {
      short8 bfr = *(const short8*)(WvT + (size_t)(tj * 16 + l15) * CDIM + ks + lg * 8);
#pragma unroll
      for (int t = 0; t < 3; t++) a2[t][tj] = MFMA16(afr[t], bfr, a2[t][tj]);
    }
  }
  unsigned short* Pb = Pbf + (size_t)b * GSZ;
#pragma unroll
  for (int t = 0; t < 3; t++)
#pragma unroll
    for (int tj = 0; tj < 12; tj++)
#pragma unroll
      for (int r = 0; r < 4; r++)
        Pb[(size_t)(row0 + t * 16 + lg * 4 + r) * CDIM + tj * 16 + l15] = bf16u_rne(a2[t][tj][r]);
}

// ---------------- Kernel D: out = P @ input (128-col chunks, v1) ------------
__global__ __launch_bounds__(256) void kD(const unsigned short* __restrict__ Pbf,
                                          const float* __restrict__ input,
                                          float* __restrict__ out) {
  const int nchunk = blockIdx.x, b = blockIdx.y;
  const int n0 = nchunk * 128;
  __shared__ __align__(16) char BsT[128 * 384];
  const int tid = threadIdx.x, wave = tid >> 6, lane = tid & 63;
  const int l15 = lane & 15, lg = lane >> 4, row0 = wave * 48;

  {
    const int n4 = (tid & 31) * 4;
    const int kb0 = (tid >> 5) * 4;
    const float* src = input + (size_t)b * CDIM * HW + n0 + n4;
    f32x4 w[24];
#pragma unroll
    for (int rnd = 0; rnd < 6; ++rnd)
#pragma unroll
      for (int j = 0; j < 4; ++j)
        w[rnd * 4 + j] = *(const f32x4*)(src + (size_t)(kb0 + rnd * 32 + j) * HW);
    __builtin_amdgcn_sched_barrier(0);
    char* bsb = BsT;
#pragma unroll
    for (int rnd = 0; rnd < 6; ++rnd) {
      const int kb = kb0 + rnd * 32;
#pragma unroll
      for (int i = 0; i < 4; ++i) {
        const int n = n4 + i;
        unsigned long long pk =
            (unsigned long long)pack_rne(w[rnd * 4 + 0][i], w[rnd * 4 + 1][i]) |
            ((unsigned long long)pack_rne(w[rnd * 4 + 2][i], w[rnd * 4 + 3][i]) << 32);
        *(unsigned long long*)(bsb + n * 384 + ((kb * 2) ^ ((n & 7) << 4))) = pk;
      }
    }
  }
  __syncthreads();

  f32x4 acc[3][8];
#pragma unroll
  for (int t = 0; t < 3; t++)
#pragma unroll
    for (int j = 0; j < 8; j++) acc[t][j] = (f32x4){0.f, 0.f, 0.f, 0.f};

  const unsigned short* Pb = Pbf + (size_t)b * GSZ;
#pragma unroll 2
  for (int ks = 0; ks < 6; ks++) {
    short8 afr[3];
#pragma unroll
    for (int t = 0; t < 3; t++)
      afr[t] = *(const short8*)(Pb + (size_t)(row0 + t * 16 + l15) * CDIM + ks * 32 + lg * 8);
#pragma unroll
    for (int tn = 0; tn < 8; tn++) {
      const int n = tn * 16 + l15;
      short8 bfr = *(const short8*)(BsT + n * 384 + ((ks * 64 + lg * 16) ^ ((n & 7) << 4)));
#pragma unroll
      for (int t = 0; t < 3; t++) acc[t][tn] = MFMA16(afr[t], bfr, acc[t][tn]);
    }
  }
  float* ob = out + (size_t)b * CDIM * HW + n0;
#pragma unroll
  for (int t = 0; t < 3; t++)
#pragma unroll
    for (int tn = 0; tn < 8; tn++)
#pragma unroll
      for (int r = 0; r < 4; r++) {
        const int m = row0 + t * 16 + lg * 4 + r;
        ob[(size_t)m * HW + tn * 16 + l15] = acc[t][tn][r];
      }
}

// ---------------- launch ----------------
extern "C" void kernel_launch(void* const* d_in, const int* in_sizes, int n_in,
                              void* d_out, int out_size, void* d_ws, size_t ws_size,
                              hipStream_t stream) {
  const float* input = (const float*)d_in[0];
  const float* color = (const float*)d_in[1];
  const float* Wq = (const float*)d_in[2];
  const float* Wk = (const float*)d_in[3];
  const float* Wv = (const float*)d_in[4];
  const float* Wo = (const float*)d_in[5];
  float* out = (float*)d_out;
  char* ws = (char*)d_ws;

  const size_t OFF_G = 0;                        // 3*8*192*192*4 = 3538944
  const size_t OFF_APRE = 3538944;               // 8*192*192*4  = 1179648
  const size_t OFF_NQK = OFF_APRE + 1179648;     // 2*8*192*4    = 12288
  const size_t OFF_ATT = OFF_NQK + 12288;        // 8*8*24*24*4  = 147456
  const size_t OFF_WVT = OFF_ATT + 147456;       // 192*192*2    = 73728
  const size_t OFF_PBF = OFF_WVT + 73728;        // 8*192*192*2  = 589824

  float* G = (float*)(ws + OFF_G);
  float* A_pre = (float*)(ws + OFF_APRE);
  float* nqk = (float*)(ws + OFF_NQK);
  float* attnw = (float*)(ws + OFF_ATT);
  unsigned short* WvT = (unsigned short*)(ws + OFF_WVT);
  unsigned short* Pbf = (unsigned short*)(ws + OFF_PBF);

  // Partials (bf16 blocked records) in d_out scratch:
  // 32*8*300*512 = 39,321,600 B <= out_size*4 = 100,663,296 B.
  // reduce_k consumes them before kD overwrites d_out.
  unsigned long long* part = (unsigned long long*)d_out;

  k0_wvt<<<dim3(144), dim3(256), 0, stream>>>(Wv, WvT);
  gram2_k<<<dim3(NPART, NB), dim3(768), 0, stream>>>(input, color, part);
  reduce_k<NPART><<<dim3(75, NB), dim3(256), 0, stream>>>(part, G);
  k2a<<<dim3(NB, 3), dim3(256), 0, stream>>>(G, Wq, Wk, A_pre, nqk);
  k2b<<<dim3(NB), dim3(256), 0, stream>>>(A_pre, nqk, attnw);
  k3<<<dim3(NB), dim3(256), 0, stream>>>(attnw, Wo, WvT, Pbf);
  kD<<<dim3(HW / 128, NB), dim3(256), 0, stream>>>(Pbf, input, out);
}